// Round 1
// baseline (26893.378 us; speedup 1.0000x reference)
//
#include <hip/hip_runtime.h>
#include <cstdint>
#include <cstddef>

#define L_NUM 8
#define D_DIM 1024
#define H_NUM 16
#define C_DIM 64
#define M_DIM 4096
#define V_DIM 64
#define B_SZ 4
#define T_SZ 2048
#define N_TOK (B_SZ * T_SZ)
#define TMAXP 2048

typedef __bf16 bf16;
typedef bf16 bf16x4 __attribute__((ext_vector_type(4)));
typedef bf16 bf16x8 __attribute__((ext_vector_type(8)));
typedef float f32x4v __attribute__((ext_vector_type(4)));

// ---------------------------------------------------------------- convert f32 -> bf16
__global__ __launch_bounds__(256) void convert_kernel(const float* __restrict__ src,
                                                      bf16* __restrict__ dst, int n) {
    int i = (blockIdx.x * 256 + threadIdx.x) * 4;
    if (i >= n) return;
    const float4 v = *(const float4*)(src + i);
    bf16x4 o;
    o[0] = (bf16)v.x; o[1] = (bf16)v.y; o[2] = (bf16)v.z; o[3] = (bf16)v.w;
    *(bf16x4*)(dst + i) = o;
}

// ---------------------------------------------------------------- embedding (fp32, K=64)
__global__ __launch_bounds__(256) void embed_kernel(const float* __restrict__ toks,
                                                    const float* __restrict__ wtok,
                                                    const float* __restrict__ wpos,
                                                    float* __restrict__ x) {
    const int n = blockIdx.x;
    const int t = n & (T_SZ - 1);
    const int tid = threadIdx.x;
    __shared__ float tl[V_DIM];
    if (tid < V_DIM) tl[tid] = toks[(size_t)n * V_DIM + tid];
    __syncthreads();
    const int d0 = tid * 4;
    float acc[4];
#pragma unroll
    for (int i = 0; i < 4; ++i) {
        const float4* w4 = (const float4*)(wtok + (size_t)(d0 + i) * V_DIM);
        const float4* t4 = (const float4*)tl;
        float a = 0.f;
#pragma unroll
        for (int vb = 0; vb < 16; ++vb) {
            float4 wv = w4[vb]; float4 tv = t4[vb];
            a += wv.x * tv.x + wv.y * tv.y + wv.z * tv.z + wv.w * tv.w;
        }
        acc[i] = a + wpos[(size_t)(d0 + i) * TMAXP + t];
    }
    float4 o = make_float4(acc[0], acc[1], acc[2], acc[3]);
    *(float4*)(x + (size_t)n * D_DIM + d0) = o;
}

// ---------------------------------------------------------------- layernorm (fp32 in, bf16 out)
__global__ __launch_bounds__(256) void ln_kernel(const float* __restrict__ x,
                                                 const float* __restrict__ g,
                                                 const float* __restrict__ b,
                                                 bf16* __restrict__ y) {
    const int n = blockIdx.x, tid = threadIdx.x;
    const float4 v = ((const float4*)(x + (size_t)n * D_DIM))[tid];
    float s = v.x + v.y + v.z + v.w;
    float q = v.x * v.x + v.y * v.y + v.z * v.z + v.w * v.w;
#pragma unroll
    for (int off = 32; off > 0; off >>= 1) {
        s += __shfl_xor(s, off);
        q += __shfl_xor(q, off);
    }
    __shared__ float s1[4], s2[4];
    if ((tid & 63) == 0) { s1[tid >> 6] = s; s2[tid >> 6] = q; }
    __syncthreads();
    s = s1[0] + s1[1] + s1[2] + s1[3];
    q = s2[0] + s2[1] + s2[2] + s2[3];
    const float mu = s * (1.f / D_DIM);
    const float var = q * (1.f / D_DIM) - mu * mu;
    const float rs = rsqrtf(var + 1e-5f);
    const float4 gg = ((const float4*)g)[tid];
    const float4 bb = ((const float4*)b)[tid];
    bf16x4 o;
    o[0] = (bf16)((v.x - mu) * rs * gg.x + bb.x);
    o[1] = (bf16)((v.y - mu) * rs * gg.y + bb.y);
    o[2] = (bf16)((v.z - mu) * rs * gg.z + bb.z);
    o[3] = (bf16)((v.w - mu) * rs * gg.w + bb.w);
    ((bf16x4*)(y + (size_t)n * D_DIM))[tid] = o;
}

// ---------------------------------------------------------------- GEMM: C[M,N] = A[M,K] @ W[N,K]^T
// 128x128 tile, BK=32, 4 waves, each wave 4x4 frags of mfma_f32_16x16x32_bf16.
// MODE 0: store bf16. MODE 1: +bias, relu, store bf16. MODE 2: +bias +add1 +add2, store f32 (in-place x).
template <int MODE>
__global__ __launch_bounds__(256) void gemm_bt(const bf16* __restrict__ A,
                                               const bf16* __restrict__ W,
                                               const float* __restrict__ bias,
                                               const float* add1, const float* add2,
                                               float* outF, bf16* outB, int K, int Nc) {
    __shared__ bf16 As[128][40];  // +8 pad: 2-way max bank aliasing on b128 frag reads
    __shared__ bf16 Bs[128][40];
    const int tid = threadIdx.x;
    const int lane = tid & 63, w = tid >> 6;
    const int wm = w >> 1, wn = w & 1;
    const int l15 = lane & 15, quad = lane >> 4;
    const size_t rowbase = (size_t)blockIdx.y * 128;
    const size_t colbase = (size_t)blockIdx.x * 128;
    f32x4v acc[4][4] = {};
    const int srow = tid >> 1;
    const int scol = (tid & 1) * 16;
    const bf16* Ap = A + (rowbase + srow) * (size_t)K + scol;
    const bf16* Wp = W + (colbase + srow) * (size_t)K + scol;
    uint4 ra0 = *(const uint4*)(Ap);
    uint4 ra1 = *(const uint4*)(Ap + 8);
    uint4 rb0 = *(const uint4*)(Wp);
    uint4 rb1 = *(const uint4*)(Wp + 8);
    for (int k0 = 0; k0 < K; k0 += 32) {
        __syncthreads();
        *(uint4*)&As[srow][scol] = ra0;
        *(uint4*)&As[srow][scol + 8] = ra1;
        *(uint4*)&Bs[srow][scol] = rb0;
        *(uint4*)&Bs[srow][scol + 8] = rb1;
        __syncthreads();
        if (k0 + 32 < K) {  // prefetch next tile (overlaps MFMA below)
            ra0 = *(const uint4*)(Ap + k0 + 32);
            ra1 = *(const uint4*)(Ap + k0 + 40);
            rb0 = *(const uint4*)(Wp + k0 + 32);
            rb1 = *(const uint4*)(Wp + k0 + 40);
        }
        bf16x8 af[4], bv[4];
#pragma unroll
        for (int f = 0; f < 4; ++f) {
            af[f] = *(const bf16x8*)&As[wm * 64 + f * 16 + l15][quad * 8];
            bv[f] = *(const bf16x8*)&Bs[wn * 64 + f * 16 + l15][quad * 8];
        }
#pragma unroll
        for (int fm = 0; fm < 4; ++fm)
#pragma unroll
            for (int fn = 0; fn < 4; ++fn)
                acc[fm][fn] = __builtin_amdgcn_mfma_f32_16x16x32_bf16(af[fm], bv[fn], acc[fm][fn], 0, 0, 0);
    }
    float bcol[4];
    if (MODE >= 1) {
#pragma unroll
        for (int fn = 0; fn < 4; ++fn) bcol[fn] = bias[colbase + wn * 64 + fn * 16 + l15];
    }
#pragma unroll
    for (int fm = 0; fm < 4; ++fm) {
#pragma unroll
        for (int r = 0; r < 4; ++r) {
            const size_t row = rowbase + wm * 64 + fm * 16 + quad * 4 + r;
            const size_t base = row * (size_t)Nc + colbase + wn * 64 + l15;
#pragma unroll
            for (int fn = 0; fn < 4; ++fn) {
                float v = acc[fm][fn][r];
                const size_t idx = base + fn * 16;
                if (MODE == 0) {
                    outB[idx] = (bf16)v;
                } else if (MODE == 1) {
                    v += bcol[fn];
                    outB[idx] = (bf16)fmaxf(v, 0.f);
                } else {
                    v += bcol[fn] + add1[idx] + add2[idx];
                    outF[idx] = v;
                }
            }
        }
    }
}

// ---------------------------------------------------------------- flash attention (fp32 VALU)
// grid (T/64, H, B), 256 threads. 64x64 Q tile; iterate causal K/V tiles with online softmax.
// thread (w,lane): qg=lane>>4, sg=lane&15 -> owns S/O block rows q0..q0+3, cols/channels s0..s0+3.
__global__ __launch_bounds__(256) void attn_kernel(const bf16* __restrict__ qkv,
                                                   const float* __restrict__ x,
                                                   float* __restrict__ h) {
    const int qt = blockIdx.x, hh = blockIdx.y, b = blockIdx.z;
    const int tid = threadIdx.x;
    const int lane = tid & 63, w = tid >> 6;
    const int qg = lane >> 4, sg = lane & 15;
    const int q0 = w * 16 + qg * 4;
    const int s0 = sg * 4;
    __shared__ float Qs[64][64];   // [q][j], pre-scaled by 1/8
    __shared__ float Ktf[64][64];  // transposed: [j][s]
    __shared__ float Vs[64][64];   // [s][ch]
    __shared__ float Ps[64][64];   // [q][s]
#pragma unroll
    for (int p = 0; p < 2; ++p) {
        int idx = p * 2048 + tid * 8;
        int r = idx >> 6, c = idx & 63;
        const bf16* src = qkv + ((size_t)(b * T_SZ + qt * 64 + r)) * (3 * D_DIM) + hh * 192 + c;
        bf16x8 qv = *(const bf16x8*)src;
#pragma unroll
        for (int j = 0; j < 8; ++j) Qs[r][c + j] = (float)qv[j] * 0.125f;
    }
    float4 O4[4];
    float m_[4], l_[4], al_[4];
#pragma unroll
    for (int i = 0; i < 4; ++i) { O4[i] = make_float4(0, 0, 0, 0); m_[i] = -1e30f; l_[i] = 0.f; }
    for (int st = 0; st <= qt; ++st) {
        __syncthreads();  // protects Ktf/Vs reuse (and Qs visibility on first iter)
#pragma unroll
        for (int p = 0; p < 2; ++p) {
            int idx = p * 2048 + tid * 8;
            int r = idx >> 6, c = idx & 63;
            const bf16* src = qkv + ((size_t)(b * T_SZ + st * 64 + r)) * (3 * D_DIM) + hh * 192 + 64 + c;
            bf16x8 kv = *(const bf16x8*)src;
            bf16x8 vv = *(const bf16x8*)(src + 64);
#pragma unroll
            for (int j = 0; j < 8; ++j) Ktf[c + j][r] = (float)kv[j];
#pragma unroll
            for (int j = 0; j < 8; ++j) Vs[r][c + j] = (float)vv[j];
        }
        __syncthreads();
        // phase 1: S = Q K^T (4x4 per thread)
        float4 S4[4];
#pragma unroll
        for (int i = 0; i < 4; ++i) S4[i] = make_float4(0, 0, 0, 0);
#pragma unroll
        for (int jb = 0; jb < 16; ++jb) {
            float4 kv0 = *(const float4*)&Ktf[jb * 4 + 0][s0];
            float4 kv1 = *(const float4*)&Ktf[jb * 4 + 1][s0];
            float4 kv2 = *(const float4*)&Ktf[jb * 4 + 2][s0];
            float4 kv3 = *(const float4*)&Ktf[jb * 4 + 3][s0];
#pragma unroll
            for (int i = 0; i < 4; ++i) {
                float4 qv = *(const float4*)&Qs[q0 + i][jb * 4];
                S4[i] += kv0 * qv.x + kv1 * qv.y + kv2 * qv.z + kv3 * qv.w;
            }
        }
        const bool diag = (st == qt);
#pragma unroll
        for (int i = 0; i < 4; ++i) {
            if (diag) {
                const int qr = q0 + i;
                if (s0 + 0 > qr) S4[i].x = -1e30f;
                if (s0 + 1 > qr) S4[i].y = -1e30f;
                if (s0 + 2 > qr) S4[i].z = -1e30f;
                if (s0 + 3 > qr) S4[i].w = -1e30f;
            }
            float mx = fmaxf(fmaxf(S4[i].x, S4[i].y), fmaxf(S4[i].z, S4[i].w));
            mx = fmaxf(mx, __shfl_xor(mx, 1));
            mx = fmaxf(mx, __shfl_xor(mx, 2));
            mx = fmaxf(mx, __shfl_xor(mx, 4));
            mx = fmaxf(mx, __shfl_xor(mx, 8));
            const float mnew = fmaxf(m_[i], mx);
            float4 P;
            P.x = __expf(S4[i].x - mnew);
            P.y = __expf(S4[i].y - mnew);
            P.z = __expf(S4[i].z - mnew);
            P.w = __expf(S4[i].w - mnew);
            float sum = P.x + P.y + P.z + P.w;
            sum += __shfl_xor(sum, 1);
            sum += __shfl_xor(sum, 2);
            sum += __shfl_xor(sum, 4);
            sum += __shfl_xor(sum, 8);
            const float a = __expf(m_[i] - mnew);
            l_[i] = l_[i] * a + sum;
            m_[i] = mnew;
            al_[i] = a;
            *(float4*)&Ps[q0 + i][s0] = P;  // intra-wave only; lgkmcnt ordering suffices
        }
        // phase 2: O = O*alpha + P V
#pragma unroll
        for (int i = 0; i < 4; ++i) {
            O4[i].x *= al_[i]; O4[i].y *= al_[i]; O4[i].z *= al_[i]; O4[i].w *= al_[i];
        }
#pragma unroll
        for (int sb = 0; sb < 16; ++sb) {
            float4 v0 = *(const float4*)&Vs[sb * 4 + 0][s0];
            float4 v1 = *(const float4*)&Vs[sb * 4 + 1][s0];
            float4 v2 = *(const float4*)&Vs[sb * 4 + 2][s0];
            float4 v3 = *(const float4*)&Vs[sb * 4 + 3][s0];
#pragma unroll
            for (int i = 0; i < 4; ++i) {
                float4 pv = *(const float4*)&Ps[q0 + i][sb * 4];
                O4[i] += v0 * pv.x + v1 * pv.y + v2 * pv.z + v3 * pv.w;
            }
        }
    }
#pragma unroll
    for (int i = 0; i < 4; ++i) {
        const size_t n = (size_t)(b * T_SZ + qt * 64 + q0 + i);
        const size_t idx = n * D_DIM + (size_t)hh * 64 + s0;
        float4 xv = *(const float4*)(x + idx);
        const float inv = 1.f / l_[i];
        float4 o;
        o.x = xv.x + O4[i].x * inv;
        o.y = xv.y + O4[i].y * inv;
        o.z = xv.z + O4[i].z * inv;
        o.w = xv.w + O4[i].w * inv;
        *(float4*)(h + idx) = o;
    }
}

// ---------------------------------------------------------------- unembed (N=64, fp32 out)
__global__ __launch_bounds__(256) void unembed_kernel(const bf16* __restrict__ lnf,
                                                      const float* __restrict__ wun,
                                                      const float* __restrict__ bun,
                                                      float* __restrict__ out) {
    const int n = blockIdx.x, tid = threadIdx.x;
    __shared__ float xr[D_DIM];
    __shared__ float part[4][V_DIM];
    const bf16x4 xv = ((const bf16x4*)(lnf + (size_t)n * D_DIM))[tid];
    xr[tid * 4 + 0] = (float)xv[0];
    xr[tid * 4 + 1] = (float)xv[1];
    xr[tid * 4 + 2] = (float)xv[2];
    xr[tid * 4 + 3] = (float)xv[3];
    __syncthreads();
    const int v = tid & 63, sl = tid >> 6;
    const float4* w4 = (const float4*)(wun + (size_t)v * D_DIM + sl * 256);
    const float4* x4 = (const float4*)(xr + sl * 256);
    float a = 0.f;
#pragma unroll
    for (int i = 0; i < 64; ++i) {
        float4 wv = w4[i]; float4 xv4 = x4[i];
        a += wv.x * xv4.x + wv.y * xv4.y + wv.z * xv4.z + wv.w * xv4.w;
    }
    part[sl][v] = a;
    __syncthreads();
    if (tid < 64)
        out[(size_t)n * V_DIM + tid] =
            part[0][tid] + part[1][tid] + part[2][tid] + part[3][tid] + bun[tid];
}

// ---------------------------------------------------------------- host
extern "C" void kernel_launch(void* const* d_in, const int* in_sizes, int n_in,
                              void* d_out, int out_size, void* d_ws, size_t ws_size,
                              hipStream_t stream) {
    (void)in_sizes; (void)n_in; (void)out_size; (void)ws_size;
    const float* toks = (const float*)d_in[0];
    const float* wtok = (const float*)d_in[1];
    const float* wpos = (const float*)d_in[2];
    const float* wqkv = (const float*)d_in[3];
    const float* g1   = (const float*)d_in[4];
    const float* be1  = (const float*)d_in[5];
    const float* w1   = (const float*)d_in[6];
    const float* bm1  = (const float*)d_in[7];
    const float* w2   = (const float*)d_in[8];
    const float* bm2  = (const float*)d_in[9];
    const float* g2   = (const float*)d_in[10];
    const float* be2  = (const float*)d_in[11];
    const float* gf   = (const float*)d_in[12];
    const float* bfp  = (const float*)d_in[13];
    const float* wun  = (const float*)d_in[14];
    const float* bun  = (const float*)d_in[15];
    float* out = (float*)d_out;

    char* ws = (char*)d_ws;
    float* xf = (float*)ws;  ws += (size_t)N_TOK * D_DIM * 4;
    float* hf = (float*)ws;  ws += (size_t)N_TOK * D_DIM * 4;
    bf16* lnb  = (bf16*)ws;  ws += (size_t)N_TOK * D_DIM * 2;
    bf16* qkvb = (bf16*)ws;  ws += (size_t)N_TOK * 3 * D_DIM * 2;
    bf16* a1b  = (bf16*)ws;  ws += (size_t)N_TOK * M_DIM * 2;
    bf16* wqb  = (bf16*)ws;  ws += (size_t)3 * D_DIM * D_DIM * 2;
    bf16* w1b  = (bf16*)ws;  ws += (size_t)M_DIM * D_DIM * 2;
    bf16* w2b  = (bf16*)ws;  ws += (size_t)D_DIM * M_DIM * 2;
    // total ws use: ~225 MB

    embed_kernel<<<N_TOK, 256, 0, stream>>>(toks, wtok, wpos, xf);
    for (int l = 0; l < L_NUM; ++l) {
        convert_kernel<<<(3 * D_DIM * D_DIM) / 1024, 256, 0, stream>>>(
            wqkv + (size_t)l * 3 * D_DIM * D_DIM, wqb, 3 * D_DIM * D_DIM);
        ln_kernel<<<N_TOK, 256, 0, stream>>>(xf, g1 + l * D_DIM, be1 + l * D_DIM, lnb);
        gemm_bt<0><<<dim3(3 * D_DIM / 128, N_TOK / 128), 256, 0, stream>>>(
            lnb, wqb, nullptr, nullptr, nullptr, nullptr, qkvb, D_DIM, 3 * D_DIM);
        attn_kernel<<<dim3(T_SZ / 64, H_NUM, B_SZ), 256, 0, stream>>>(qkvb, xf, hf);
        ln_kernel<<<N_TOK, 256, 0, stream>>>(hf, g2 + l * D_DIM, be2 + l * D_DIM, lnb);
        convert_kernel<<<(M_DIM * D_DIM) / 1024, 256, 0, stream>>>(
            w1 + (size_t)l * M_DIM * D_DIM, w1b, M_DIM * D_DIM);
        gemm_bt<1><<<dim3(M_DIM / 128, N_TOK / 128), 256, 0, stream>>>(
            lnb, w1b, bm1 + l * M_DIM, nullptr, nullptr, nullptr, a1b, D_DIM, M_DIM);
        convert_kernel<<<(D_DIM * M_DIM) / 1024, 256, 0, stream>>>(
            w2 + (size_t)l * D_DIM * M_DIM, w2b, D_DIM * M_DIM);
        gemm_bt<2><<<dim3(D_DIM / 128, N_TOK / 128), 256, 0, stream>>>(
            a1b, w2b, bm2 + l * D_DIM, xf, hf, xf, nullptr, M_DIM, D_DIM);
    }
    ln_kernel<<<N_TOK, 256, 0, stream>>>(xf, gf, bfp, lnb);
    unembed_kernel<<<N_TOK, 256, 0, stream>>>(lnb, wun, bun, out);
}

// Round 2
// 5240.519 us; speedup vs baseline: 5.1318x; 5.1318x over previous
//
#include <hip/hip_runtime.h>
#include <cstdint>
#include <cstddef>

#define L_NUM 8
#define D_DIM 1024
#define H_NUM 16
#define C_DIM 64
#define M_DIM 4096
#define V_DIM 64
#define B_SZ 4
#define T_SZ 2048
#define N_TOK (B_SZ * T_SZ)
#define TMAXP 2048

typedef __bf16 bf16;
typedef bf16 bf16x4 __attribute__((ext_vector_type(4)));
typedef bf16 bf16x8 __attribute__((ext_vector_type(8)));
typedef float f32x4v __attribute__((ext_vector_type(4)));

// ---------------------------------------------------------------- convert f32 -> bf16
__global__ __launch_bounds__(256) void convert_kernel(const float* __restrict__ src,
                                                      bf16* __restrict__ dst, int n) {
    int i = (blockIdx.x * 256 + threadIdx.x) * 4;
    if (i >= n) return;
    const float4 v = *(const float4*)(src + i);
    bf16x4 o;
    o[0] = (bf16)v.x; o[1] = (bf16)v.y; o[2] = (bf16)v.z; o[3] = (bf16)v.w;
    *(bf16x4*)(dst + i) = o;
}

// ---------------------------------------------------------------- embedding (fp32, K=64)
__global__ __launch_bounds__(256) void embed_kernel(const float* __restrict__ toks,
                                                    const float* __restrict__ wtok,
                                                    const float* __restrict__ wpos,
                                                    float* __restrict__ x) {
    const int n = blockIdx.x;
    const int t = n & (T_SZ - 1);
    const int tid = threadIdx.x;
    __shared__ float tl[V_DIM];
    if (tid < V_DIM) tl[tid] = toks[(size_t)n * V_DIM + tid];
    __syncthreads();
    const int d0 = tid * 4;
    float acc[4];
#pragma unroll
    for (int i = 0; i < 4; ++i) {
        const float4* w4 = (const float4*)(wtok + (size_t)(d0 + i) * V_DIM);
        const float4* t4 = (const float4*)tl;
        float a = 0.f;
#pragma unroll
        for (int vb = 0; vb < 16; ++vb) {
            float4 wv = w4[vb]; float4 tv = t4[vb];
            a += wv.x * tv.x + wv.y * tv.y + wv.z * tv.z + wv.w * tv.w;
        }
        acc[i] = a + wpos[(size_t)(d0 + i) * TMAXP + t];
    }
    float4 o = make_float4(acc[0], acc[1], acc[2], acc[3]);
    *(float4*)(x + (size_t)n * D_DIM + d0) = o;
}

// ---------------------------------------------------------------- layernorm (fp32 in, bf16 out)
__global__ __launch_bounds__(256) void ln_kernel(const float* __restrict__ x,
                                                 const float* __restrict__ g,
                                                 const float* __restrict__ b,
                                                 bf16* __restrict__ y) {
    const int n = blockIdx.x, tid = threadIdx.x;
    const float4 v = ((const float4*)(x + (size_t)n * D_DIM))[tid];
    float s = v.x + v.y + v.z + v.w;
    float q = v.x * v.x + v.y * v.y + v.z * v.z + v.w * v.w;
#pragma unroll
    for (int off = 32; off > 0; off >>= 1) {
        s += __shfl_xor(s, off);
        q += __shfl_xor(q, off);
    }
    __shared__ float s1[4], s2[4];
    if ((tid & 63) == 0) { s1[tid >> 6] = s; s2[tid >> 6] = q; }
    __syncthreads();
    s = s1[0] + s1[1] + s1[2] + s1[3];
    q = s2[0] + s2[1] + s2[2] + s2[3];
    const float mu = s * (1.f / D_DIM);
    const float var = q * (1.f / D_DIM) - mu * mu;
    const float rs = rsqrtf(var + 1e-5f);
    const float4 gg = ((const float4*)g)[tid];
    const float4 bb = ((const float4*)b)[tid];
    bf16x4 o;
    o[0] = (bf16)((v.x - mu) * rs * gg.x + bb.x);
    o[1] = (bf16)((v.y - mu) * rs * gg.y + bb.y);
    o[2] = (bf16)((v.z - mu) * rs * gg.z + bb.z);
    o[3] = (bf16)((v.w - mu) * rs * gg.w + bb.w);
    ((bf16x4*)(y + (size_t)n * D_DIM))[tid] = o;
}

// ---------------------------------------------------------------- GEMM: C[M,N] = A[M,K] @ W[N,K]^T
// 128x128 tile, BK=32, 4 waves, each wave 4x4 frags of mfma_f32_16x16x32_bf16.
// MODE 0: store bf16. MODE 1: +bias, relu, store bf16. MODE 2: +bias +add1 +add2, store f32 (in-place x).
template <int MODE>
__global__ __launch_bounds__(256) void gemm_bt(const bf16* __restrict__ A,
                                               const bf16* __restrict__ W,
                                               const float* __restrict__ bias,
                                               const float* add1, const float* add2,
                                               float* outF, bf16* outB, int K, int Nc) {
    __shared__ bf16 As[128][40];  // +8 pad: 2-way max bank aliasing on b128 frag reads
    __shared__ bf16 Bs[128][40];
    const int tid = threadIdx.x;
    const int lane = tid & 63, w = tid >> 6;
    const int wm = w >> 1, wn = w & 1;
    const int l15 = lane & 15, quad = lane >> 4;
    const size_t rowbase = (size_t)blockIdx.y * 128;
    const size_t colbase = (size_t)blockIdx.x * 128;
    f32x4v acc[4][4] = {};
    const int srow = tid >> 1;
    const int scol = (tid & 1) * 16;
    const bf16* Ap = A + (rowbase + srow) * (size_t)K + scol;
    const bf16* Wp = W + (colbase + srow) * (size_t)K + scol;
    uint4 ra0 = *(const uint4*)(Ap);
    uint4 ra1 = *(const uint4*)(Ap + 8);
    uint4 rb0 = *(const uint4*)(Wp);
    uint4 rb1 = *(const uint4*)(Wp + 8);
    for (int k0 = 0; k0 < K; k0 += 32) {
        __syncthreads();
        *(uint4*)&As[srow][scol] = ra0;
        *(uint4*)&As[srow][scol + 8] = ra1;
        *(uint4*)&Bs[srow][scol] = rb0;
        *(uint4*)&Bs[srow][scol + 8] = rb1;
        __syncthreads();
        if (k0 + 32 < K) {  // prefetch next tile (overlaps MFMA below)
            ra0 = *(const uint4*)(Ap + k0 + 32);
            ra1 = *(const uint4*)(Ap + k0 + 40);
            rb0 = *(const uint4*)(Wp + k0 + 32);
            rb1 = *(const uint4*)(Wp + k0 + 40);
        }
        bf16x8 af[4], bv[4];
#pragma unroll
        for (int f = 0; f < 4; ++f) {
            af[f] = *(const bf16x8*)&As[wm * 64 + f * 16 + l15][quad * 8];
            bv[f] = *(const bf16x8*)&Bs[wn * 64 + f * 16 + l15][quad * 8];
        }
#pragma unroll
        for (int fm = 0; fm < 4; ++fm)
#pragma unroll
            for (int fn = 0; fn < 4; ++fn)
                acc[fm][fn] = __builtin_amdgcn_mfma_f32_16x16x32_bf16(af[fm], bv[fn], acc[fm][fn], 0, 0, 0);
    }
    float bcol[4];
    if (MODE >= 1) {
#pragma unroll
        for (int fn = 0; fn < 4; ++fn) bcol[fn] = bias[colbase + wn * 64 + fn * 16 + l15];
    }
#pragma unroll
    for (int fm = 0; fm < 4; ++fm) {
#pragma unroll
        for (int r = 0; r < 4; ++r) {
            const size_t row = rowbase + wm * 64 + fm * 16 + quad * 4 + r;
            const size_t base = row * (size_t)Nc + colbase + wn * 64 + l15;
#pragma unroll
            for (int fn = 0; fn < 4; ++fn) {
                float v = acc[fm][fn][r];
                const size_t idx = base + fn * 16;
                if (MODE == 0) {
                    outB[idx] = (bf16)v;
                } else if (MODE == 1) {
                    v += bcol[fn];
                    outB[idx] = (bf16)fmaxf(v, 0.f);
                } else {
                    v += bcol[fn] + add1[idx] + add2[idx];
                    outF[idx] = v;
                }
            }
        }
    }
}

// ---------------------------------------------------------------- MFMA flash attention
// grid (T/128, H, B), 256 threads = 4 waves. Each block: 128 q rows; wave w owns rows [w*32, w*32+32).
// Iterate 64-wide K/V tiles causally with fp32 online softmax; QK^T and PV on mfma_f32_16x16x32_bf16.
// C/D layout: row = quad*4+r, col = lane&15. A/B frag: X[idx=lane&15][k=quad*8+j].
__global__ __launch_bounds__(256) void attn_kernel(const bf16* __restrict__ qkv,
                                                   const float* __restrict__ x,
                                                   float* __restrict__ h) {
    const int qt = blockIdx.x, hh = blockIdx.y, b = blockIdx.z;
    const int tid = threadIdx.x;
    const int lane = tid & 63, w = tid >> 6;
    const int quad = lane >> 4, l15 = lane & 15;

    __shared__ __align__(16) bf16 Ks[64][72];      // [s][ch], 144B rows (16B-aligned frag reads)
    __shared__ __align__(16) bf16 Vt[64][72];      // [ch][s] transposed
    __shared__ __align__(16) bf16 Ps[4][32][72];   // per-wave P round-trip (C-layout -> A-layout)

    // Q fragments (held in registers all kernel): Q[q=l15][ch=kc*32+quad*8+j]
    bf16x8 Qf[2][2];
#pragma unroll
    for (int qsub = 0; qsub < 2; ++qsub)
#pragma unroll
        for (int kc = 0; kc < 2; ++kc)
            Qf[qsub][kc] = *(const bf16x8*)(qkv +
                ((size_t)(b * T_SZ + qt * 128 + w * 32 + qsub * 16 + l15)) * (3 * D_DIM) +
                hh * 192 + kc * 32 + quad * 8);

    f32x4v accO[2][4] = {};
    float m_[2][4], l_[2][4], alp[2][4];
#pragma unroll
    for (int i = 0; i < 2; ++i)
#pragma unroll
        for (int r = 0; r < 4; ++r) { m_[i][r] = -1e30f; l_[i][r] = 0.f; }

    const int nst = 2 * qt + 2;
    for (int st = 0; st < nst; ++st) {
        const int sbase = st * 64;
        __syncthreads();  // protect Ks/Vt against previous iteration's readers
        // --- stage K (row-major, b128 writes, conflict-free) ---
#pragma unroll
        for (int p = 0; p < 2; ++p) {
            const int r = p * 32 + (tid >> 3);
            const int c = (tid & 7) * 8;
            *(bf16x8*)&Ks[r][c] = *(const bf16x8*)(qkv +
                ((size_t)(b * T_SZ + sbase + r)) * (3 * D_DIM) + hh * 192 + 64 + c);
        }
        // --- stage V transposed: column-gather from global (coalesced 2B/lane), contiguous LDS write ---
#pragma unroll
        for (int task = 0; task < 2; ++task) {
            const int ch = tid & 63;
            const int s0 = ((tid >> 6) + task * 4) * 8;
            const bf16* vsrc = qkv + ((size_t)(b * T_SZ + sbase + s0)) * (3 * D_DIM) +
                               hh * 192 + 128 + ch;
            bf16x8 vv;
#pragma unroll
            for (int j = 0; j < 8; ++j) vv[j] = vsrc[(size_t)j * (3 * D_DIM)];
            *(bf16x8*)&Vt[ch][s0] = vv;
        }
        __syncthreads();

        // waves whose entire q range is above this tile skip compute (barriers stay uniform)
        if (sbase <= qt * 128 + w * 32 + 31) {
            // --- S = Q K^T ---
            f32x4v Sacc[2][4] = {};
#pragma unroll
            for (int ssub = 0; ssub < 4; ++ssub)
#pragma unroll
                for (int kc = 0; kc < 2; ++kc) {
                    bf16x8 Kf = *(const bf16x8*)&Ks[ssub * 16 + l15][kc * 32 + quad * 8];
#pragma unroll
                    for (int qsub = 0; qsub < 2; ++qsub)
                        Sacc[qsub][ssub] =
                            __builtin_amdgcn_mfma_f32_16x16x32_bf16(Qf[qsub][kc], Kf, Sacc[qsub][ssub], 0, 0, 0);
                }
            // --- online softmax (fp32) ---
#pragma unroll
            for (int qsub = 0; qsub < 2; ++qsub) {
                const int qb = qt * 128 + w * 32 + qsub * 16;  // min q row of this subtile
                float sv[4][4];  // [r][ssub], scaled
#pragma unroll
                for (int r = 0; r < 4; ++r)
#pragma unroll
                    for (int ssub = 0; ssub < 4; ++ssub) sv[r][ssub] = Sacc[qsub][ssub][r] * 0.125f;
                if (sbase + 63 > qb) {  // causal mask needed
#pragma unroll
                    for (int ssub = 0; ssub < 4; ++ssub) {
                        const int s = sbase + ssub * 16 + l15;
#pragma unroll
                        for (int r = 0; r < 4; ++r)
                            if (s > qb + quad * 4 + r) sv[r][ssub] = -1e38f;
                    }
                }
#pragma unroll
                for (int r = 0; r < 4; ++r) {
                    float mx = fmaxf(fmaxf(sv[r][0], sv[r][1]), fmaxf(sv[r][2], sv[r][3]));
                    mx = fmaxf(mx, __shfl_xor(mx, 1));
                    mx = fmaxf(mx, __shfl_xor(mx, 2));
                    mx = fmaxf(mx, __shfl_xor(mx, 4));
                    mx = fmaxf(mx, __shfl_xor(mx, 8));
                    const float mold = m_[qsub][r];
                    const float mnew = fmaxf(mold, mx);
                    const float al = __expf(mold - mnew);
                    float p0 = __expf(sv[r][0] - mnew);
                    float p1 = __expf(sv[r][1] - mnew);
                    float p2 = __expf(sv[r][2] - mnew);
                    float p3 = __expf(sv[r][3] - mnew);
                    float rs = p0 + p1 + p2 + p3;
                    rs += __shfl_xor(rs, 1);
                    rs += __shfl_xor(rs, 2);
                    rs += __shfl_xor(rs, 4);
                    rs += __shfl_xor(rs, 8);
                    l_[qsub][r] = l_[qsub][r] * al + rs;
                    m_[qsub][r] = mnew;
                    alp[qsub][r] = al;
                    const int qrow = qsub * 16 + quad * 4 + r;
                    Ps[w][qrow][0 * 16 + l15] = (bf16)p0;
                    Ps[w][qrow][1 * 16 + l15] = (bf16)p1;
                    Ps[w][qrow][2 * 16 + l15] = (bf16)p2;
                    Ps[w][qrow][3 * 16 + l15] = (bf16)p3;
                }
            }
            // --- rescale O by alpha ---
#pragma unroll
            for (int qsub = 0; qsub < 2; ++qsub)
#pragma unroll
                for (int nsub = 0; nsub < 4; ++nsub)
#pragma unroll
                    for (int r = 0; r < 4; ++r) accO[qsub][nsub][r] *= alp[qsub][r];
            // --- O += P V (P via LDS round-trip to A-layout; Vt rows give B-frags) ---
#pragma unroll
            for (int kc2 = 0; kc2 < 2; ++kc2) {
                bf16x8 Pf[2];
#pragma unroll
                for (int qsub = 0; qsub < 2; ++qsub)
                    Pf[qsub] = *(const bf16x8*)&Ps[w][qsub * 16 + l15][kc2 * 32 + quad * 8];
#pragma unroll
                for (int nsub = 0; nsub < 4; ++nsub) {
                    bf16x8 Vf = *(const bf16x8*)&Vt[nsub * 16 + l15][kc2 * 32 + quad * 8];
#pragma unroll
                    for (int qsub = 0; qsub < 2; ++qsub)
                        accO[qsub][nsub] =
                            __builtin_amdgcn_mfma_f32_16x16x32_bf16(Pf[qsub], Vf, accO[qsub][nsub], 0, 0, 0);
                }
            }
        }
    }
    // --- epilogue: h = x + O / l ---
#pragma unroll
    for (int qsub = 0; qsub < 2; ++qsub)
#pragma unroll
        for (int r = 0; r < 4; ++r) {
            const float inv = 1.f / l_[qsub][r];
            const size_t row = (size_t)(b * T_SZ + qt * 128 + w * 32 + qsub * 16 + quad * 4 + r);
            const size_t base = row * D_DIM + (size_t)hh * 64 + l15;
#pragma unroll
            for (int nsub = 0; nsub < 4; ++nsub) {
                const size_t idx = base + nsub * 16;
                h[idx] = x[idx] + accO[qsub][nsub][r] * inv;
            }
        }
}

// ---------------------------------------------------------------- unembed (N=64, fp32 out)
__global__ __launch_bounds__(256) void unembed_kernel(const bf16* __restrict__ lnf,
                                                      const float* __restrict__ wun,
                                                      const float* __restrict__ bun,
                                                      float* __restrict__ out) {
    const int n = blockIdx.x, tid = threadIdx.x;
    __shared__ float xr[D_DIM];
    __shared__ float part[4][V_DIM];
    const bf16x4 xv = ((const bf16x4*)(lnf + (size_t)n * D_DIM))[tid];
    xr[tid * 4 + 0] = (float)xv[0];
    xr[tid * 4 + 1] = (float)xv[1];
    xr[tid * 4 + 2] = (float)xv[2];
    xr[tid * 4 + 3] = (float)xv[3];
    __syncthreads();
    const int v = tid & 63, sl = tid >> 6;
    const float4* w4 = (const float4*)(wun + (size_t)v * D_DIM + sl * 256);
    const float4* x4 = (const float4*)(xr + sl * 256);
    float a = 0.f;
#pragma unroll
    for (int i = 0; i < 64; ++i) {
        float4 wv = w4[i]; float4 xv4 = x4[i];
        a += wv.x * xv4.x + wv.y * xv4.y + wv.z * xv4.z + wv.w * xv4.w;
    }
    part[sl][v] = a;
    __syncthreads();
    if (tid < 64)
        out[(size_t)n * V_DIM + tid] =
            part[0][tid] + part[1][tid] + part[2][tid] + part[3][tid] + bun[tid];
}

// ---------------------------------------------------------------- host
extern "C" void kernel_launch(void* const* d_in, const int* in_sizes, int n_in,
                              void* d_out, int out_size, void* d_ws, size_t ws_size,
                              hipStream_t stream) {
    (void)in_sizes; (void)n_in; (void)out_size; (void)ws_size;
    const float* toks = (const float*)d_in[0];
    const float* wtok = (const float*)d_in[1];
    const float* wpos = (const float*)d_in[2];
    const float* wqkv = (const float*)d_in[3];
    const float* g1   = (const float*)d_in[4];
    const float* be1  = (const float*)d_in[5];
    const float* w1   = (const float*)d_in[6];
    const float* bm1  = (const float*)d_in[7];
    const float* w2   = (const float*)d_in[8];
    const float* bm2  = (const float*)d_in[9];
    const float* g2   = (const float*)d_in[10];
    const float* be2  = (const float*)d_in[11];
    const float* gf   = (const float*)d_in[12];
    const float* bfp  = (const float*)d_in[13];
    const float* wun  = (const float*)d_in[14];
    const float* bun  = (const float*)d_in[15];
    float* out = (float*)d_out;

    char* ws = (char*)d_ws;
    float* xf = (float*)ws;  ws += (size_t)N_TOK * D_DIM * 4;
    float* hf = (float*)ws;  ws += (size_t)N_TOK * D_DIM * 4;
    bf16* lnb  = (bf16*)ws;  ws += (size_t)N_TOK * D_DIM * 2;
    bf16* qkvb = (bf16*)ws;  ws += (size_t)N_TOK * 3 * D_DIM * 2;
    bf16* a1b  = (bf16*)ws;  ws += (size_t)N_TOK * M_DIM * 2;
    bf16* wqb  = (bf16*)ws;  ws += (size_t)3 * D_DIM * D_DIM * 2;
    bf16* w1b  = (bf16*)ws;  ws += (size_t)M_DIM * D_DIM * 2;
    bf16* w2b  = (bf16*)ws;  ws += (size_t)D_DIM * M_DIM * 2;

    embed_kernel<<<N_TOK, 256, 0, stream>>>(toks, wtok, wpos, xf);
    for (int l = 0; l < L_NUM; ++l) {
        convert_kernel<<<(3 * D_DIM * D_DIM) / 1024, 256, 0, stream>>>(
            wqkv + (size_t)l * 3 * D_DIM * D_DIM, wqb, 3 * D_DIM * D_DIM);
        ln_kernel<<<N_TOK, 256, 0, stream>>>(xf, g1 + l * D_DIM, be1 + l * D_DIM, lnb);
        gemm_bt<0><<<dim3(3 * D_DIM / 128, N_TOK / 128), 256, 0, stream>>>(
            lnb, wqb, nullptr, nullptr, nullptr, nullptr, qkvb, D_DIM, 3 * D_DIM);
        attn_kernel<<<dim3(T_SZ / 128, H_NUM, B_SZ), 256, 0, stream>>>(qkvb, xf, hf);
        ln_kernel<<<N_TOK, 256, 0, stream>>>(hf, g2 + l * D_DIM, be2 + l * D_DIM, lnb);
        convert_kernel<<<(M_DIM * D_DIM) / 1024, 256, 0, stream>>>(
            w1 + (size_t)l * M_DIM * D_DIM, w1b, M_DIM * D_DIM);
        gemm_bt<1><<<dim3(M_DIM / 128, N_TOK / 128), 256, 0, stream>>>(
            lnb, w1b, bm1 + l * M_DIM, nullptr, nullptr, nullptr, a1b, D_DIM, M_DIM);
        convert_kernel<<<(D_DIM * M_DIM) / 1024, 256, 0, stream>>>(
            w2 + (size_t)l * D_DIM * M_DIM, w2b, D_DIM * M_DIM);
        gemm_bt<2><<<dim3(D_DIM / 128, N_TOK / 128), 256, 0, stream>>>(
            a1b, w2b, bm2 + l * D_DIM, xf, hf, xf, nullptr, M_DIM, D_DIM);
    }
    ln_kernel<<<N_TOK, 256, 0, stream>>>(xf, gf, bfp, lnb);
    unembed_kernel<<<N_TOK, 256, 0, stream>>>(lnb, wun, bun, out);
}

// Round 3
// 4281.698 us; speedup vs baseline: 6.2810x; 1.2239x over previous
//
#include <hip/hip_runtime.h>
#include <cstdint>
#include <cstddef>

#define L_NUM 8
#define D_DIM 1024
#define H_NUM 16
#define C_DIM 64
#define M_DIM 4096
#define V_DIM 64
#define B_SZ 4
#define T_SZ 2048
#define N_TOK (B_SZ * T_SZ)
#define TMAXP 2048

typedef __bf16 bf16;
typedef bf16 bf16x4 __attribute__((ext_vector_type(4)));
typedef bf16 bf16x8 __attribute__((ext_vector_type(8)));
typedef float f32x4v __attribute__((ext_vector_type(4)));

// async global->LDS, 16B per lane. LDS dest = wave-uniform base + lane*16.
__device__ __forceinline__ void async16(const bf16* g, bf16* l) {
    __builtin_amdgcn_global_load_lds(
        (const __attribute__((address_space(1))) void*)g,
        (__attribute__((address_space(3))) void*)l, 16, 0, 0);
}

// ---------------------------------------------------------------- convert f32 -> bf16
__global__ __launch_bounds__(256) void convert_kernel(const float* __restrict__ src,
                                                      bf16* __restrict__ dst, int n) {
    int i = (blockIdx.x * 256 + threadIdx.x) * 4;
    if (i >= n) return;
    const float4 v = *(const float4*)(src + i);
    bf16x4 o;
    o[0] = (bf16)v.x; o[1] = (bf16)v.y; o[2] = (bf16)v.z; o[3] = (bf16)v.w;
    *(bf16x4*)(dst + i) = o;
}

// ---------------------------------------------------------------- wpos [D][TMAX] -> posT [TMAX][D]
__global__ __launch_bounds__(256) void transpose_pos(const float* __restrict__ in,
                                                     float* __restrict__ out) {
    __shared__ float tile[32][33];
    const int t0 = blockIdx.x * 32, d0 = blockIdx.y * 32;
    const int tx = threadIdx.x & 31, ty = threadIdx.x >> 5;
#pragma unroll
    for (int j = 0; j < 32; j += 8)
        tile[ty + j][tx] = in[(size_t)(d0 + ty + j) * TMAXP + t0 + tx];
    __syncthreads();
#pragma unroll
    for (int j = 0; j < 32; j += 8)
        out[(size_t)(t0 + ty + j) * D_DIM + d0 + tx] = tile[tx][ty + j];
}

// ---------------------------------------------------------------- layernorm (fp32 in, bf16 out)
__global__ __launch_bounds__(256) void ln_kernel(const float* __restrict__ x,
                                                 const float* __restrict__ g,
                                                 const float* __restrict__ b,
                                                 bf16* __restrict__ y) {
    const int n = blockIdx.x, tid = threadIdx.x;
    const float4 v = ((const float4*)(x + (size_t)n * D_DIM))[tid];
    float s = v.x + v.y + v.z + v.w;
    float q = v.x * v.x + v.y * v.y + v.z * v.z + v.w * v.w;
#pragma unroll
    for (int off = 32; off > 0; off >>= 1) {
        s += __shfl_xor(s, off);
        q += __shfl_xor(q, off);
    }
    __shared__ float s1[4], s2[4];
    if ((tid & 63) == 0) { s1[tid >> 6] = s; s2[tid >> 6] = q; }
    __syncthreads();
    s = s1[0] + s1[1] + s1[2] + s1[3];
    q = s2[0] + s2[1] + s2[2] + s2[3];
    const float mu = s * (1.f / D_DIM);
    const float var = q * (1.f / D_DIM) - mu * mu;
    const float rs = rsqrtf(var + 1e-5f);
    const float4 gg = ((const float4*)g)[tid];
    const float4 bb = ((const float4*)b)[tid];
    bf16x4 o;
    o[0] = (bf16)((v.x - mu) * rs * gg.x + bb.x);
    o[1] = (bf16)((v.y - mu) * rs * gg.y + bb.y);
    o[2] = (bf16)((v.z - mu) * rs * gg.z + bb.z);
    o[3] = (bf16)((v.w - mu) * rs * gg.w + bb.w);
    ((bf16x4*)(y + (size_t)n * D_DIM))[tid] = o;
}

// ---------------------------------------------------------------- GEMM: C[M,N] = A[M,K] @ W[N,K]^T
// 128x128 tile, BK=64, global_load_lds width-16 staging with XOR-8 chunk swizzle
// (LDS chunk s of row r holds global chunk s^(r&7) -> conflict-free frag reads, no padding).
// MODE 0: store bf16. MODE 1: +bias, relu, bf16. MODE 2: +bias+add1+add2, f32.
// MODE 3: +posT[(row%T)*Nc+col] (add1=posT), f32.
template <int MODE>
__global__ __launch_bounds__(256) void gemm_bt(const bf16* __restrict__ A,
                                               const bf16* __restrict__ W,
                                               const float* __restrict__ bias,
                                               const float* add1, const float* add2,
                                               float* outF, bf16* outB, int K, int Nc) {
    __shared__ __align__(16) bf16 As[128][64];
    __shared__ __align__(16) bf16 Bs[128][64];
    const int tid = threadIdx.x;
    const int lane = tid & 63, w = tid >> 6;
    const int wm = w >> 1, wn = w & 1;
    const int l15 = lane & 15, quad = lane >> 4;
    const size_t rowbase = (size_t)blockIdx.y * 128;
    const size_t colbase = (size_t)blockIdx.x * 128;
    f32x4v acc[4][4] = {};
    // staging: instruction i covers 8 rows (1024B); lane -> row w*32+i*8+(lane>>3), lds chunk lane&7
    const int rsub = lane >> 3;
    const int schunk = lane & 7;
    const int gchunk = schunk ^ rsub;  // swizzled global source chunk
    const bf16* Ag = A + (rowbase + w * 32 + rsub) * (size_t)K + gchunk * 8;
    const bf16* Wg = W + (colbase + w * 32 + rsub) * (size_t)K + gchunk * 8;
    bf16* Asl = &As[w * 32][0];
    bf16* Bsl = &Bs[w * 32][0];
    const int swz = l15 & 7;
    for (int k0 = 0; k0 < K; k0 += 64) {
        __syncthreads();
#pragma unroll
        for (int i = 0; i < 4; ++i) {
            async16(Ag + k0 + (size_t)(i * 8) * K, Asl + i * 512);
            async16(Wg + k0 + (size_t)(i * 8) * K, Bsl + i * 512);
        }
        __syncthreads();  // compiler emits vmcnt(0) drain here
#pragma unroll
        for (int kk = 0; kk < 2; ++kk) {
            const int q = kk * 4 + quad;
            bf16x8 af[4], bv[4];
#pragma unroll
            for (int f = 0; f < 4; ++f) {
                af[f] = *(const bf16x8*)&As[wm * 64 + f * 16 + l15][(q ^ swz) * 8];
                bv[f] = *(const bf16x8*)&Bs[wn * 64 + f * 16 + l15][(q ^ swz) * 8];
            }
#pragma unroll
            for (int fm = 0; fm < 4; ++fm)
#pragma unroll
                for (int fn = 0; fn < 4; ++fn)
                    acc[fm][fn] = __builtin_amdgcn_mfma_f32_16x16x32_bf16(af[fm], bv[fn], acc[fm][fn], 0, 0, 0);
        }
    }
    float bcol[4];
    if (MODE == 1 || MODE == 2) {
#pragma unroll
        for (int fn = 0; fn < 4; ++fn) bcol[fn] = bias[colbase + wn * 64 + fn * 16 + l15];
    }
#pragma unroll
    for (int fm = 0; fm < 4; ++fm) {
#pragma unroll
        for (int r = 0; r < 4; ++r) {
            const size_t row = rowbase + wm * 64 + fm * 16 + quad * 4 + r;
            const size_t base = row * (size_t)Nc + colbase + wn * 64 + l15;
#pragma unroll
            for (int fn = 0; fn < 4; ++fn) {
                float v = acc[fm][fn][r];
                const size_t idx = base + fn * 16;
                if (MODE == 0) {
                    outB[idx] = (bf16)v;
                } else if (MODE == 1) {
                    v += bcol[fn];
                    outB[idx] = (bf16)fmaxf(v, 0.f);
                } else if (MODE == 2) {
                    v += bcol[fn] + add1[idx] + add2[idx];
                    outF[idx] = v;
                } else {  // MODE 3: embedding epilogue, add transposed pos-embedding
                    const size_t t = row & (T_SZ - 1);
                    const size_t col = colbase + wn * 64 + fn * 16 + l15;
                    v += add1[t * (size_t)Nc + col];
                    outF[idx] = v;
                }
            }
        }
    }
}

// ---------------------------------------------------------------- MFMA flash attention
// grid (T/128, H, B), 256 threads = 4 waves; wave w owns q rows [w*32, w*32+32).
__global__ __launch_bounds__(256) void attn_kernel(const bf16* __restrict__ qkv,
                                                   const float* __restrict__ x,
                                                   float* __restrict__ h) {
    const int qt = blockIdx.x, hh = blockIdx.y, b = blockIdx.z;
    const int tid = threadIdx.x;
    const int lane = tid & 63, w = tid >> 6;
    const int quad = lane >> 4, l15 = lane & 15;

    __shared__ __align__(16) bf16 Ks[64][72];
    __shared__ __align__(16) bf16 Vt[64][72];
    __shared__ __align__(16) bf16 Ps[4][32][72];

    bf16x8 Qf[2][2];
#pragma unroll
    for (int qsub = 0; qsub < 2; ++qsub)
#pragma unroll
        for (int kc = 0; kc < 2; ++kc)
            Qf[qsub][kc] = *(const bf16x8*)(qkv +
                ((size_t)(b * T_SZ + qt * 128 + w * 32 + qsub * 16 + l15)) * (3 * D_DIM) +
                hh * 192 + kc * 32 + quad * 8);

    f32x4v accO[2][4] = {};
    float m_[2][4], l_[2][4], alp[2][4];
#pragma unroll
    for (int i = 0; i < 2; ++i)
#pragma unroll
        for (int r = 0; r < 4; ++r) { m_[i][r] = -1e30f; l_[i][r] = 0.f; }

    const int nst = 2 * qt + 2;
    for (int st = 0; st < nst; ++st) {
        const int sbase = st * 64;
        __syncthreads();
#pragma unroll
        for (int p = 0; p < 2; ++p) {
            const int r = p * 32 + (tid >> 3);
            const int c = (tid & 7) * 8;
            *(bf16x8*)&Ks[r][c] = *(const bf16x8*)(qkv +
                ((size_t)(b * T_SZ + sbase + r)) * (3 * D_DIM) + hh * 192 + 64 + c);
        }
#pragma unroll
        for (int task = 0; task < 2; ++task) {
            const int ch = tid & 63;
            const int s0 = ((tid >> 6) + task * 4) * 8;
            const bf16* vsrc = qkv + ((size_t)(b * T_SZ + sbase + s0)) * (3 * D_DIM) +
                               hh * 192 + 128 + ch;
            bf16x8 vv;
#pragma unroll
            for (int j = 0; j < 8; ++j) vv[j] = vsrc[(size_t)j * (3 * D_DIM)];
            *(bf16x8*)&Vt[ch][s0] = vv;
        }
        __syncthreads();

        if (sbase <= qt * 128 + w * 32 + 31) {
            f32x4v Sacc[2][4] = {};
#pragma unroll
            for (int ssub = 0; ssub < 4; ++ssub)
#pragma unroll
                for (int kc = 0; kc < 2; ++kc) {
                    bf16x8 Kf = *(const bf16x8*)&Ks[ssub * 16 + l15][kc * 32 + quad * 8];
#pragma unroll
                    for (int qsub = 0; qsub < 2; ++qsub)
                        Sacc[qsub][ssub] =
                            __builtin_amdgcn_mfma_f32_16x16x32_bf16(Qf[qsub][kc], Kf, Sacc[qsub][ssub], 0, 0, 0);
                }
#pragma unroll
            for (int qsub = 0; qsub < 2; ++qsub) {
                const int qb = qt * 128 + w * 32 + qsub * 16;
                float sv[4][4];
#pragma unroll
                for (int r = 0; r < 4; ++r)
#pragma unroll
                    for (int ssub = 0; ssub < 4; ++ssub) sv[r][ssub] = Sacc[qsub][ssub][r] * 0.125f;
                if (sbase + 63 > qb) {
#pragma unroll
                    for (int ssub = 0; ssub < 4; ++ssub) {
                        const int s = sbase + ssub * 16 + l15;
#pragma unroll
                        for (int r = 0; r < 4; ++r)
                            if (s > qb + quad * 4 + r) sv[r][ssub] = -1e38f;
                    }
                }
#pragma unroll
                for (int r = 0; r < 4; ++r) {
                    float mx = fmaxf(fmaxf(sv[r][0], sv[r][1]), fmaxf(sv[r][2], sv[r][3]));
                    mx = fmaxf(mx, __shfl_xor(mx, 1));
                    mx = fmaxf(mx, __shfl_xor(mx, 2));
                    mx = fmaxf(mx, __shfl_xor(mx, 4));
                    mx = fmaxf(mx, __shfl_xor(mx, 8));
                    const float mold = m_[qsub][r];
                    const float mnew = fmaxf(mold, mx);
                    const float al = __expf(mold - mnew);
                    float p0 = __expf(sv[r][0] - mnew);
                    float p1 = __expf(sv[r][1] - mnew);
                    float p2 = __expf(sv[r][2] - mnew);
                    float p3 = __expf(sv[r][3] - mnew);
                    float rs = p0 + p1 + p2 + p3;
                    rs += __shfl_xor(rs, 1);
                    rs += __shfl_xor(rs, 2);
                    rs += __shfl_xor(rs, 4);
                    rs += __shfl_xor(rs, 8);
                    l_[qsub][r] = l_[qsub][r] * al + rs;
                    m_[qsub][r] = mnew;
                    alp[qsub][r] = al;
                    const int qrow = qsub * 16 + quad * 4 + r;
                    Ps[w][qrow][0 * 16 + l15] = (bf16)p0;
                    Ps[w][qrow][1 * 16 + l15] = (bf16)p1;
                    Ps[w][qrow][2 * 16 + l15] = (bf16)p2;
                    Ps[w][qrow][3 * 16 + l15] = (bf16)p3;
                }
            }
#pragma unroll
            for (int qsub = 0; qsub < 2; ++qsub)
#pragma unroll
                for (int nsub = 0; nsub < 4; ++nsub)
#pragma unroll
                    for (int r = 0; r < 4; ++r) accO[qsub][nsub][r] *= alp[qsub][r];
#pragma unroll
            for (int kc2 = 0; kc2 < 2; ++kc2) {
                bf16x8 Pf[2];
#pragma unroll
                for (int qsub = 0; qsub < 2; ++qsub)
                    Pf[qsub] = *(const bf16x8*)&Ps[w][qsub * 16 + l15][kc2 * 32 + quad * 8];
#pragma unroll
                for (int nsub = 0; nsub < 4; ++nsub) {
                    bf16x8 Vf = *(const bf16x8*)&Vt[nsub * 16 + l15][kc2 * 32 + quad * 8];
#pragma unroll
                    for (int qsub = 0; qsub < 2; ++qsub)
                        accO[qsub][nsub] =
                            __builtin_amdgcn_mfma_f32_16x16x32_bf16(Pf[qsub], Vf, accO[qsub][nsub], 0, 0, 0);
                }
            }
        }
    }
#pragma unroll
    for (int qsub = 0; qsub < 2; ++qsub)
#pragma unroll
        for (int r = 0; r < 4; ++r) {
            const float inv = 1.f / l_[qsub][r];
            const size_t row = (size_t)(b * T_SZ + qt * 128 + w * 32 + qsub * 16 + quad * 4 + r);
            const size_t base = row * D_DIM + (size_t)hh * 64 + l15;
#pragma unroll
            for (int nsub = 0; nsub < 4; ++nsub) {
                const size_t idx = base + nsub * 16;
                h[idx] = x[idx] + accO[qsub][nsub][r] * inv;
            }
        }
}

// ---------------------------------------------------------------- unembed MFMA: out[M,64] = A[M,1024] @ W[64,1024]^T + bun
// 64 blocks x 128 rows; wave w: rows w*32..+32, all 64 cols.
__global__ __launch_bounds__(256) void unembed_kernel(const bf16* __restrict__ A,
                                                      const bf16* __restrict__ W,
                                                      const float* __restrict__ bun,
                                                      float* __restrict__ out) {
    __shared__ __align__(16) bf16 As[128][64];
    __shared__ __align__(16) bf16 Ws[64][64];
    const int tid = threadIdx.x, lane = tid & 63, w = tid >> 6;
    const int l15 = lane & 15, quad = lane >> 4;
    const size_t rowbase = (size_t)blockIdx.x * 128;
    const int rsub = lane >> 3, schunk = lane & 7, gchunk = schunk ^ rsub;
    const bf16* Ag = A + (rowbase + w * 32 + rsub) * (size_t)D_DIM + gchunk * 8;
    const bf16* Wg = W + (w * 16 + rsub) * (size_t)D_DIM + gchunk * 8;
    bf16* Asl = &As[w * 32][0];
    bf16* Wsl = &Ws[w * 16][0];
    const int swz = l15 & 7;
    f32x4v acc[2][4] = {};
    for (int k0 = 0; k0 < D_DIM; k0 += 64) {
        __syncthreads();
#pragma unroll
        for (int i = 0; i < 4; ++i)
            async16(Ag + k0 + (size_t)(i * 8) * D_DIM, Asl + i * 512);
#pragma unroll
        for (int i = 0; i < 2; ++i)
            async16(Wg + k0 + (size_t)(i * 8) * D_DIM, Wsl + i * 512);
        __syncthreads();
#pragma unroll
        for (int kk = 0; kk < 2; ++kk) {
            const int q = kk * 4 + quad;
            bf16x8 af[2], bv[4];
#pragma unroll
            for (int f = 0; f < 2; ++f) af[f] = *(const bf16x8*)&As[w * 32 + f * 16 + l15][(q ^ swz) * 8];
#pragma unroll
            for (int f = 0; f < 4; ++f) bv[f] = *(const bf16x8*)&Ws[f * 16 + l15][(q ^ swz) * 8];
#pragma unroll
            for (int fm = 0; fm < 2; ++fm)
#pragma unroll
                for (int fn = 0; fn < 4; ++fn)
                    acc[fm][fn] = __builtin_amdgcn_mfma_f32_16x16x32_bf16(af[fm], bv[fn], acc[fm][fn], 0, 0, 0);
        }
    }
#pragma unroll
    for (int fm = 0; fm < 2; ++fm)
#pragma unroll
        for (int r = 0; r < 4; ++r) {
            const size_t row = rowbase + w * 32 + fm * 16 + quad * 4 + r;
#pragma unroll
            for (int fn = 0; fn < 4; ++fn) {
                const int col = fn * 16 + l15;
                out[row * V_DIM + col] = acc[fm][fn][r] + bun[col];
            }
        }
}

// ---------------------------------------------------------------- host
extern "C" void kernel_launch(void* const* d_in, const int* in_sizes, int n_in,
                              void* d_out, int out_size, void* d_ws, size_t ws_size,
                              hipStream_t stream) {
    (void)in_sizes; (void)n_in; (void)out_size; (void)ws_size;
    const float* toks = (const float*)d_in[0];
    const float* wtok = (const float*)d_in[1];
    const float* wpos = (const float*)d_in[2];
    const float* wqkv = (const float*)d_in[3];
    const float* g1   = (const float*)d_in[4];
    const float* be1  = (const float*)d_in[5];
    const float* w1   = (const float*)d_in[6];
    const float* bm1  = (const float*)d_in[7];
    const float* w2   = (const float*)d_in[8];
    const float* bm2  = (const float*)d_in[9];
    const float* g2   = (const float*)d_in[10];
    const float* be2  = (const float*)d_in[11];
    const float* gf   = (const float*)d_in[12];
    const float* bfp  = (const float*)d_in[13];
    const float* wun  = (const float*)d_in[14];
    const float* bun  = (const float*)d_in[15];
    float* out = (float*)d_out;

    char* ws = (char*)d_ws;
    float* xf = (float*)ws;  ws += (size_t)N_TOK * D_DIM * 4;
    float* hf = (float*)ws;  ws += (size_t)N_TOK * D_DIM * 4;
    bf16* lnb  = (bf16*)ws;  ws += (size_t)N_TOK * D_DIM * 2;
    bf16* qkvb = (bf16*)ws;  ws += (size_t)N_TOK * 3 * D_DIM * 2;
    bf16* a1b  = (bf16*)ws;  ws += (size_t)N_TOK * M_DIM * 2;
    bf16* wqb  = (bf16*)ws;  ws += (size_t)3 * D_DIM * D_DIM * 2;
    bf16* w1b  = (bf16*)ws;  ws += (size_t)M_DIM * D_DIM * 2;
    bf16* w2b  = (bf16*)ws;  ws += (size_t)D_DIM * M_DIM * 2;
    bf16* toksb = (bf16*)ws; ws += (size_t)N_TOK * V_DIM * 2;
    bf16* wtokb = (bf16*)ws; ws += (size_t)D_DIM * V_DIM * 2;
    bf16* wunb  = (bf16*)ws; ws += (size_t)V_DIM * D_DIM * 2;
    float* posT = (float*)ws; ws += (size_t)TMAXP * D_DIM * 4;

    // ---- embedding: x = toks @ W_tok^T + posT ----
    convert_kernel<<<(N_TOK * V_DIM) / 1024, 256, 0, stream>>>(toks, toksb, N_TOK * V_DIM);
    convert_kernel<<<(D_DIM * V_DIM) / 1024, 256, 0, stream>>>(wtok, wtokb, D_DIM * V_DIM);
    transpose_pos<<<dim3(TMAXP / 32, D_DIM / 32), 256, 0, stream>>>(wpos, posT);
    gemm_bt<3><<<dim3(D_DIM / 128, N_TOK / 128), 256, 0, stream>>>(
        toksb, wtokb, nullptr, posT, nullptr, xf, nullptr, V_DIM, D_DIM);

    for (int l = 0; l < L_NUM; ++l) {
        convert_kernel<<<(3 * D_DIM * D_DIM) / 1024, 256, 0, stream>>>(
            wqkv + (size_t)l * 3 * D_DIM * D_DIM, wqb, 3 * D_DIM * D_DIM);
        ln_kernel<<<N_TOK, 256, 0, stream>>>(xf, g1 + l * D_DIM, be1 + l * D_DIM, lnb);
        gemm_bt<0><<<dim3(3 * D_DIM / 128, N_TOK / 128), 256, 0, stream>>>(
            lnb, wqb, nullptr, nullptr, nullptr, nullptr, qkvb, D_DIM, 3 * D_DIM);
        attn_kernel<<<dim3(T_SZ / 128, H_NUM, B_SZ), 256, 0, stream>>>(qkvb, xf, hf);
        ln_kernel<<<N_TOK, 256, 0, stream>>>(hf, g2 + l * D_DIM, be2 + l * D_DIM, lnb);
        convert_kernel<<<(M_DIM * D_DIM) / 1024, 256, 0, stream>>>(
            w1 + (size_t)l * M_DIM * D_DIM, w1b, M_DIM * D_DIM);
        gemm_bt<1><<<dim3(M_DIM / 128, N_TOK / 128), 256, 0, stream>>>(
            lnb, w1b, bm1 + l * M_DIM, nullptr, nullptr, nullptr, a1b, D_DIM, M_DIM);
        convert_kernel<<<(D_DIM * M_DIM) / 1024, 256, 0, stream>>>(
            w2 + (size_t)l * D_DIM * M_DIM, w2b, D_DIM * M_DIM);
        gemm_bt<2><<<dim3(D_DIM / 128, N_TOK / 128), 256, 0, stream>>>(
            a1b, w2b, bm2 + l * D_DIM, xf, hf, xf, nullptr, M_DIM, D_DIM);
    }
    ln_kernel<<<N_TOK, 256, 0, stream>>>(xf, gf, bfp, lnb);
    convert_kernel<<<(V_DIM * D_DIM) / 1024, 256, 0, stream>>>(wun, wunb, V_DIM * D_DIM);
    unembed_kernel<<<N_TOK / 128, 256, 0, stream>>>(lnb, wunb, bun, out);
}

// Round 5
// 4246.808 us; speedup vs baseline: 6.3326x; 1.0082x over previous
//
#include <hip/hip_runtime.h>
#include <cstdint>
#include <cstddef>

#define L_NUM 8
#define D_DIM 1024
#define H_NUM 16
#define C_DIM 64
#define M_DIM 4096
#define V_DIM 64
#define B_SZ 4
#define T_SZ 2048
#define N_TOK (B_SZ * T_SZ)
#define TMAXP 2048
#define QKV_LD (3 * D_DIM)

typedef __bf16 bf16;
typedef bf16 bf16x4 __attribute__((ext_vector_type(4)));
typedef bf16 bf16x8 __attribute__((ext_vector_type(8)));
typedef float f32x4v __attribute__((ext_vector_type(4)));

// async global->LDS, 16B per lane. LDS dest = wave-uniform base + lane*16.
__device__ __forceinline__ void async16(const bf16* g, bf16* l) {
    __builtin_amdgcn_global_load_lds(
        (const __attribute__((address_space(1))) void*)g,
        (__attribute__((address_space(3))) void*)l, 16, 0, 0);
}

// ---------------------------------------------------------------- convert f32 -> bf16
__global__ __launch_bounds__(256) void convert_kernel(const float* __restrict__ src,
                                                      bf16* __restrict__ dst, int n) {
    int i = (blockIdx.x * 256 + threadIdx.x) * 4;
    if (i >= n) return;
    const float4 v = *(const float4*)(src + i);
    bf16x4 o;
    o[0] = (bf16)v.x; o[1] = (bf16)v.y; o[2] = (bf16)v.z; o[3] = (bf16)v.w;
    *(bf16x4*)(dst + i) = o;
}

// ---------------------------------------------------------------- wpos [D][TMAX] -> posT [TMAX][D]
__global__ __launch_bounds__(256) void transpose_pos(const float* __restrict__ in,
                                                     float* __restrict__ out) {
    __shared__ float tile[32][33];
    const int t0 = blockIdx.x * 32, d0 = blockIdx.y * 32;
    const int tx = threadIdx.x & 31, ty = threadIdx.x >> 5;
#pragma unroll
    for (int j = 0; j < 32; j += 8)
        tile[ty + j][tx] = in[(size_t)(d0 + ty + j) * TMAXP + t0 + tx];
    __syncthreads();
#pragma unroll
    for (int j = 0; j < 32; j += 8)
        out[(size_t)(t0 + ty + j) * D_DIM + d0 + tx] = tile[tx][ty + j];
}

// ---------------------------------------------------------------- layernorm (fp32 in, bf16 out)
__global__ __launch_bounds__(256) void ln_kernel(const float* __restrict__ x,
                                                 const float* __restrict__ g,
                                                 const float* __restrict__ b,
                                                 bf16* __restrict__ y) {
    const int n = blockIdx.x, tid = threadIdx.x;
    const float4 v = ((const float4*)(x + (size_t)n * D_DIM))[tid];
    float s = v.x + v.y + v.z + v.w;
    float q = v.x * v.x + v.y * v.y + v.z * v.z + v.w * v.w;
#pragma unroll
    for (int off = 32; off > 0; off >>= 1) {
        s += __shfl_xor(s, off);
        q += __shfl_xor(q, off);
    }
    __shared__ float s1[4], s2[4];
    if ((tid & 63) == 0) { s1[tid >> 6] = s; s2[tid >> 6] = q; }
    __syncthreads();
    s = s1[0] + s1[1] + s1[2] + s1[3];
    q = s2[0] + s2[1] + s2[2] + s2[3];
    const float mu = s * (1.f / D_DIM);
    const float var = q * (1.f / D_DIM) - mu * mu;
    const float rs = rsqrtf(var + 1e-5f);
    const float4 gg = ((const float4*)g)[tid];
    const float4 bb = ((const float4*)b)[tid];
    bf16x4 o;
    o[0] = (bf16)((v.x - mu) * rs * gg.x + bb.x);
    o[1] = (bf16)((v.y - mu) * rs * gg.y + bb.y);
    o[2] = (bf16)((v.z - mu) * rs * gg.z + bb.z);
    o[3] = (bf16)((v.w - mu) * rs * gg.w + bb.w);
    ((bf16x4*)(y + (size_t)n * D_DIM))[tid] = o;
}

// ---------------------------------------------------------------- GEMM: C[M,N] = A[M,K] @ W[N,K]^T
// 128x128 tile, BK=64, global_load_lds width-16 staging with XOR-8 chunk swizzle.
// MODE 0: store bf16. MODE 1: +bias, relu, bf16. MODE 2: +bias+add1+add2, f32.
// MODE 3: +posT[(row%T)*Nc+col] (add1=posT), f32.
template <int MODE>
__global__ __launch_bounds__(256) void gemm_bt(const bf16* __restrict__ A,
                                               const bf16* __restrict__ W,
                                               const float* __restrict__ bias,
                                               const float* add1, const float* add2,
                                               float* outF, bf16* outB, int K, int Nc) {
    __shared__ __align__(16) bf16 As[128][64];
    __shared__ __align__(16) bf16 Bs[128][64];
    const int tid = threadIdx.x;
    const int lane = tid & 63, w = tid >> 6;
    const int wm = w >> 1, wn = w & 1;
    const int l15 = lane & 15, quad = lane >> 4;
    const size_t rowbase = (size_t)blockIdx.y * 128;
    const size_t colbase = (size_t)blockIdx.x * 128;
    f32x4v acc[4][4] = {};
    const int rsub = lane >> 3;
    const int schunk = lane & 7;
    const int gchunk = schunk ^ rsub;
    const bf16* Ag = A + (rowbase + w * 32 + rsub) * (size_t)K + gchunk * 8;
    const bf16* Wg = W + (colbase + w * 32 + rsub) * (size_t)K + gchunk * 8;
    bf16* Asl = &As[w * 32][0];
    bf16* Bsl = &Bs[w * 32][0];
    const int swz = l15 & 7;
    for (int k0 = 0; k0 < K; k0 += 64) {
        __syncthreads();
#pragma unroll
        for (int i = 0; i < 4; ++i) {
            async16(Ag + k0 + (size_t)(i * 8) * K, Asl + i * 512);
            async16(Wg + k0 + (size_t)(i * 8) * K, Bsl + i * 512);
        }
        __syncthreads();
#pragma unroll
        for (int kk = 0; kk < 2; ++kk) {
            const int q = kk * 4 + quad;
            bf16x8 af[4], bv[4];
#pragma unroll
            for (int f = 0; f < 4; ++f) {
                af[f] = *(const bf16x8*)&As[wm * 64 + f * 16 + l15][(q ^ swz) * 8];
                bv[f] = *(const bf16x8*)&Bs[wn * 64 + f * 16 + l15][(q ^ swz) * 8];
            }
#pragma unroll
            for (int fm = 0; fm < 4; ++fm)
#pragma unroll
                for (int fn = 0; fn < 4; ++fn)
                    acc[fm][fn] = __builtin_amdgcn_mfma_f32_16x16x32_bf16(af[fm], bv[fn], acc[fm][fn], 0, 0, 0);
        }
    }
    float bcol[4];
    if (MODE == 1 || MODE == 2) {
#pragma unroll
        for (int fn = 0; fn < 4; ++fn) bcol[fn] = bias[colbase + wn * 64 + fn * 16 + l15];
    }
#pragma unroll
    for (int fm = 0; fm < 4; ++fm) {
#pragma unroll
        for (int r = 0; r < 4; ++r) {
            const size_t row = rowbase + wm * 64 + fm * 16 + quad * 4 + r;
            const size_t base = row * (size_t)Nc + colbase + wn * 64 + l15;
#pragma unroll
            for (int fn = 0; fn < 4; ++fn) {
                float v = acc[fm][fn][r];
                const size_t idx = base + fn * 16;
                if (MODE == 0) {
                    outB[idx] = (bf16)v;
                } else if (MODE == 1) {
                    v += bcol[fn];
                    outB[idx] = (bf16)fmaxf(v, 0.f);
                } else if (MODE == 2) {
                    v += bcol[fn] + add1[idx] + add2[idx];
                    outF[idx] = v;
                } else {
                    const size_t t = row & (T_SZ - 1);
                    const size_t col = colbase + wn * 64 + fn * 16 + l15;
                    v += add1[t * (size_t)Nc + col];
                    outF[idx] = v;
                }
            }
        }
    }
}

// ---------------------------------------------------------------- MFMA flash attention (S^T formulation)
// grid (T/128, H, B), 4 waves; wave w owns q rows [w*32, w*32+32). qt reversed for load balance.
// S^T = mfma(A=K, B=Q): lane holds S^T[s=quad*4+r][q=l15] -> 4 consecutive s per lane:
// softmax reduces via shfl_xor(16,32) only; P stored as b64; alpha/l realigned via __shfl.
// K/V register-prefetched one tile ahead; all LDS layouts bank-uniform.
__global__ __launch_bounds__(256) void attn_kernel(const bf16* __restrict__ qkv,
                                                   const float* __restrict__ x,
                                                   float* __restrict__ h) {
    const int qt = (int)gridDim.x - 1 - (int)blockIdx.x;  // longest strips first
    const int hh = blockIdx.y, b = blockIdx.z;
    const int tid = threadIdx.x;
    const int lane = tid & 63, w = tid >> 6;
    const int quad = lane >> 4, l15 = lane & 15;

    __shared__ __align__(16) bf16 Ks[64][64];     // XOR-swizzled chunks
    __shared__ __align__(16) bf16 Vt[64][72];     // [ch][s]
    __shared__ __align__(16) bf16 Ps[4][16][80];  // per-wave P: [q][s], pad 80

    // Q fragments: B-frag [n=q=l15][k=ch]
    bf16x8 Qf[2][2];
#pragma unroll
    for (int qsub = 0; qsub < 2; ++qsub)
#pragma unroll
        for (int kc = 0; kc < 2; ++kc)
            Qf[qsub][kc] = *(const bf16x8*)(qkv +
                ((size_t)(b * T_SZ + qt * 128 + w * 32 + qsub * 16 + l15)) * QKV_LD +
                hh * 192 + kc * 32 + quad * 8);

    f32x4v accO[2][4] = {};
    float m_[2] = {-1e30f, -1e30f}, l_[2] = {0.f, 0.f};

    const int qwave = qt * 128 + w * 32;
    const int nst = 2 * qt + 2;
    constexpr float SC = 0.125f * 1.44269504f;  // scale * log2(e)

    // staging geometry
    const int krow = lane >> 3;          // 0..7 within 8-row group
    const int kchunk = lane & 7;         // global 16B chunk
    const int kswz = kchunk ^ krow;      // LDS chunk (XOR swizzle)
    const bf16* kptr = qkv + ((size_t)(b * T_SZ) + w * 16 + krow) * QKV_LD +
                       hh * 192 + 64 + kchunk * 8;
    const bf16* vptr0 = qkv + ((size_t)(b * T_SZ) + w * 8) * QKV_LD + hh * 192 + 128 + lane;
    const bf16* vptr1 = qkv + ((size_t)(b * T_SZ) + (w + 4) * 8) * QKV_LD + hh * 192 + 128 + lane;

    // prologue prefetch (tile 0)
    uint4 kr0 = *(const uint4*)(kptr);
    uint4 kr1 = *(const uint4*)(kptr + (size_t)8 * QKV_LD);
    bf16x8 vv0, vv1;
#pragma unroll
    for (int j = 0; j < 8; ++j) { vv0[j] = vptr0[(size_t)j * QKV_LD]; vv1[j] = vptr1[(size_t)j * QKV_LD]; }
    kptr += (size_t)64 * QKV_LD; vptr0 += (size_t)64 * QKV_LD; vptr1 += (size_t)64 * QKV_LD;

    for (int st = 0; st < nst; ++st) {
        const int sbase = st * 64;
        __syncthreads();  // protect Ks/Vt against previous tile's readers
        *(uint4*)&Ks[w * 16 + krow][kswz * 8] = kr0;
        *(uint4*)&Ks[w * 16 + 8 + krow][kswz * 8] = kr1;
        *(bf16x8*)&Vt[lane][w * 8] = vv0;
        *(bf16x8*)&Vt[lane][(w + 4) * 8] = vv1;
        __syncthreads();
        if (st + 1 < nst) {  // prefetch next tile (overlaps compute below)
            kr0 = *(const uint4*)(kptr);
            kr1 = *(const uint4*)(kptr + (size_t)8 * QKV_LD);
#pragma unroll
            for (int j = 0; j < 8; ++j) { vv0[j] = vptr0[(size_t)j * QKV_LD]; vv1[j] = vptr1[(size_t)j * QKV_LD]; }
            kptr += (size_t)64 * QKV_LD; vptr0 += (size_t)64 * QKV_LD; vptr1 += (size_t)64 * QKV_LD;
        }
        if (sbase <= qwave + 31) {
#pragma unroll
            for (int qsub = 0; qsub < 2; ++qsub) {
                const int qb = qwave + qsub * 16;  // q = qb + l15
                // --- S^T = K Q^T ---
                f32x4v St[4] = {};
#pragma unroll
                for (int ssub = 0; ssub < 4; ++ssub)
#pragma unroll
                    for (int kc = 0; kc < 2; ++kc) {
                        bf16x8 Kf = *(const bf16x8*)&Ks[ssub * 16 + l15][((kc * 4 + quad) ^ (l15 & 7)) * 8];
                        St[ssub] = __builtin_amdgcn_mfma_f32_16x16x32_bf16(Kf, Qf[qsub][kc], St[ssub], 0, 0, 0);
                    }
                // --- scale to log2 domain + causal mask ---
                float sv[4][4];
#pragma unroll
                for (int ssub = 0; ssub < 4; ++ssub)
#pragma unroll
                    for (int r = 0; r < 4; ++r) sv[ssub][r] = St[ssub][r] * SC;
                if (sbase + 63 > qb) {
#pragma unroll
                    for (int ssub = 0; ssub < 4; ++ssub) {
#pragma unroll
                        for (int r = 0; r < 4; ++r) {
                            const int s = sbase + ssub * 16 + quad * 4 + r;
                            if (s > qb + l15) sv[ssub][r] = -1e38f;
                        }
                    }
                }
                // --- online softmax per q (=l15), cross-quad via shfl 16/32 ---
                float mx = sv[0][0];
#pragma unroll
                for (int ssub = 0; ssub < 4; ++ssub)
#pragma unroll
                    for (int r = 0; r < 4; ++r) mx = fmaxf(mx, sv[ssub][r]);
                mx = fmaxf(mx, __shfl_xor(mx, 16));
                mx = fmaxf(mx, __shfl_xor(mx, 32));
                const float mold = m_[qsub];
                const float mnew = fmaxf(mold, mx);
                const float al = exp2f(mold - mnew);
                float rs = 0.f;
                float p[4][4];
#pragma unroll
                for (int ssub = 0; ssub < 4; ++ssub)
#pragma unroll
                    for (int r = 0; r < 4; ++r) {
                        p[ssub][r] = exp2f(sv[ssub][r] - mnew);
                        rs += p[ssub][r];
                    }
                rs += __shfl_xor(rs, 16);
                rs += __shfl_xor(rs, 32);
                l_[qsub] = l_[qsub] * al + rs;
                m_[qsub] = mnew;
                // --- store P (b64, bank-uniform) ---
#pragma unroll
                for (int ssub = 0; ssub < 4; ++ssub) {
                    bf16x4 pk;
#pragma unroll
                    for (int r = 0; r < 4; ++r) pk[r] = (bf16)p[ssub][r];
                    *(bf16x4*)&Ps[w][l15][ssub * 16 + quad * 4] = pk;
                }
                // --- realign alpha to PV C-layout rows & rescale O ---
                float alr[4];
#pragma unroll
                for (int r = 0; r < 4; ++r) alr[r] = __shfl(al, quad * 4 + r);
#pragma unroll
                for (int nsub = 0; nsub < 4; ++nsub)
#pragma unroll
                    for (int r = 0; r < 4; ++r) accO[qsub][nsub][r] *= alr[r];
                // --- O += P V ---
#pragma unroll
                for (int kc2 = 0; kc2 < 2; ++kc2) {
                    bf16x8 Pf = *(const bf16x8*)&Ps[w][l15][kc2 * 32 + quad * 8];
#pragma unroll
                    for (int nsub = 0; nsub < 4; ++nsub) {
                        bf16x8 Vf = *(const bf16x8*)&Vt[nsub * 16 + l15][kc2 * 32 + quad * 8];
                        accO[qsub][nsub] =
                            __builtin_amdgcn_mfma_f32_16x16x32_bf16(Pf, Vf, accO[qsub][nsub], 0, 0, 0);
                    }
                }
            }
        }
    }
    // --- epilogue: h = x + O / l ---
#pragma unroll
    for (int qsub = 0; qsub < 2; ++qsub) {
        const float linv = 1.f / l_[qsub];
        float invr[4];
#pragma unroll
        for (int r = 0; r < 4; ++r) invr[r] = __shfl(linv, quad * 4 + r);
#pragma unroll
        for (int r = 0; r < 4; ++r) {
            const size_t row = (size_t)(b * T_SZ + qt * 128 + w * 32 + qsub * 16 + quad * 4 + r);
            const size_t base = row * D_DIM + (size_t)hh * 64 + l15;
#pragma unroll
            for (int nsub = 0; nsub < 4; ++nsub) {
                const size_t idx = base + nsub * 16;
                h[idx] = x[idx] + accO[qsub][nsub][r] * invr[r];
            }
        }
    }
}

// ---------------------------------------------------------------- unembed MFMA: out[M,64] = A[M,1024] @ W[64,1024]^T + bun
__global__ __launch_bounds__(256) void unembed_kernel(const bf16* __restrict__ A,
                                                      const bf16* __restrict__ W,
                                                      const float* __restrict__ bun,
                                                      float* __restrict__ out) {
    __shared__ __align__(16) bf16 As[128][64];
    __shared__ __align__(16) bf16 Ws[64][64];
    const int tid = threadIdx.x, lane = tid & 63, w = tid >> 6;
    const int l15 = lane & 15, quad = lane >> 4;
    const size_t rowbase = (size_t)blockIdx.x * 128;
    const int rsub = lane >> 3, schunk = lane & 7, gchunk = schunk ^ rsub;
    const bf16* Ag = A + (rowbase + w * 32 + rsub) * (size_t)D_DIM + gchunk * 8;
    const bf16* Wg = W + (w * 16 + rsub) * (size_t)D_DIM + gchunk * 8;
    bf16* Asl = &As[w * 32][0];
    bf16* Wsl = &Ws[w * 16][0];
    const int swz = l15 & 7;
    f32x4v acc[2][4] = {};
    for (int k0 = 0; k0 < D_DIM; k0 += 64) {
        __syncthreads();
#pragma unroll
        for (int i = 0; i < 4; ++i)
            async16(Ag + k0 + (size_t)(i * 8) * D_DIM, Asl + i * 512);
#pragma unroll
        for (int i = 0; i < 2; ++i)
            async16(Wg + k0 + (size_t)(i * 8) * D_DIM, Wsl + i * 512);
        __syncthreads();
#pragma unroll
        for (int kk = 0; kk < 2; ++kk) {
            const int q = kk * 4 + quad;
            bf16x8 af[2], bv[4];
#pragma unroll
            for (int f = 0; f < 2; ++f) af[f] = *(const bf16x8*)&As[w * 32 + f * 16 + l15][(q ^ swz) * 8];
#pragma unroll
            for (int f = 0; f < 4; ++f) bv[f] = *(const bf16x8*)&Ws[f * 16 + l15][(q ^ swz) * 8];
#pragma unroll
            for (int fm = 0; fm < 2; ++fm)
#pragma unroll
                for (int fn = 0; fn < 4; ++fn)
                    acc[fm][fn] = __builtin_amdgcn_mfma_f32_16x16x32_bf16(af[fm], bv[fn], acc[fm][fn], 0, 0, 0);
        }
    }
#pragma unroll
    for (int fm = 0; fm < 2; ++fm)
#pragma unroll
        for (int r = 0; r < 4; ++r) {
            const size_t row = rowbase + w * 32 + fm * 16 + quad * 4 + r;
#pragma unroll
            for (int fn = 0; fn < 4; ++fn) {
                const int col = fn * 16 + l15;
                out[row * V_DIM + col] = acc[fm][fn][r] + bun[col];
            }
        }
}

// ---------------------------------------------------------------- host
extern "C" void kernel_launch(void* const* d_in, const int* in_sizes, int n_in,
                              void* d_out, int out_size, void* d_ws, size_t ws_size,
                              hipStream_t stream) {
    (void)in_sizes; (void)n_in; (void)out_size; (void)ws_size;
    const float* toks = (const float*)d_in[0];
    const float* wtok = (const float*)d_in[1];
    const float* wpos = (const float*)d_in[2];
    const float* wqkv = (const float*)d_in[3];
    const float* g1   = (const float*)d_in[4];
    const float* be1  = (const float*)d_in[5];
    const float* w1   = (const float*)d_in[6];
    const float* bm1  = (const float*)d_in[7];
    const float* w2   = (const float*)d_in[8];
    const float* bm2  = (const float*)d_in[9];
    const float* g2   = (const float*)d_in[10];
    const float* be2  = (const float*)d_in[11];
    const float* gf   = (const float*)d_in[12];
    const float* bfp  = (const float*)d_in[13];
    const float* wun  = (const float*)d_in[14];
    const float* bun  = (const float*)d_in[15];
    float* out = (float*)d_out;

    char* ws = (char*)d_ws;
    float* xf = (float*)ws;  ws += (size_t)N_TOK * D_DIM * 4;
    float* hf = (float*)ws;  ws += (size_t)N_TOK * D_DIM * 4;
    bf16* lnb  = (bf16*)ws;  ws += (size_t)N_TOK * D_DIM * 2;
    bf16* qkvb = (bf16*)ws;  ws += (size_t)N_TOK * 3 * D_DIM * 2;
    bf16* a1b  = (bf16*)ws;  ws += (size_t)N_TOK * M_DIM * 2;
    bf16* wqb  = (bf16*)ws;  ws += (size_t)3 * D_DIM * D_DIM * 2;
    bf16* w1b  = (bf16*)ws;  ws += (size_t)M_DIM * D_DIM * 2;
    bf16* w2b  = (bf16*)ws;  ws += (size_t)D_DIM * M_DIM * 2;
    bf16* toksb = (bf16*)ws; ws += (size_t)N_TOK * V_DIM * 2;
    bf16* wtokb = (bf16*)ws; ws += (size_t)D_DIM * V_DIM * 2;
    bf16* wunb  = (bf16*)ws; ws += (size_t)V_DIM * D_DIM * 2;
    float* posT = (float*)ws; ws += (size_t)TMAXP * D_DIM * 4;

    convert_kernel<<<(N_TOK * V_DIM) / 1024, 256, 0, stream>>>(toks, toksb, N_TOK * V_DIM);
    convert_kernel<<<(D_DIM * V_DIM) / 1024, 256, 0, stream>>>(wtok, wtokb, D_DIM * V_DIM);
    transpose_pos<<<dim3(TMAXP / 32, D_DIM / 32), 256, 0, stream>>>(wpos, posT);
    gemm_bt<3><<<dim3(D_DIM / 128, N_TOK / 128), 256, 0, stream>>>(
        toksb, wtokb, nullptr, posT, nullptr, xf, nullptr, V_DIM, D_DIM);

    for (int l = 0; l < L_NUM; ++l) {
        convert_kernel<<<(3 * D_DIM * D_DIM) / 1024, 256, 0, stream>>>(
            wqkv + (size_t)l * 3 * D_DIM * D_DIM, wqb, 3 * D_DIM * D_DIM);
        ln_kernel<<<N_TOK, 256, 0, stream>>>(xf, g1 + l * D_DIM, be1 + l * D_DIM, lnb);
        gemm_bt<0><<<dim3(3 * D_DIM / 128, N_TOK / 128), 256, 0, stream>>>(
            lnb, wqb, nullptr, nullptr, nullptr, nullptr, qkvb, D_DIM, 3 * D_DIM);
        attn_kernel<<<dim3(T_SZ / 128, H_NUM, B_SZ), 256, 0, stream>>>(qkvb, xf, hf);
        ln_kernel<<<N_TOK, 256, 0, stream>>>(hf, g2 + l * D_DIM, be2 + l * D_DIM, lnb);
        convert_kernel<<<(M_DIM * D_DIM) / 1024, 256, 0, stream>>>(
            w1 + (size_t)l * M_DIM * D_DIM, w1b, M_DIM * D_DIM);
        gemm_bt<1><<<dim3(M_DIM / 128, N_TOK / 128), 256, 0, stream>>>(
            lnb, w1b, bm1 + l * M_DIM, nullptr, nullptr, nullptr, a1b, D_DIM, M_DIM);
        convert_kernel<<<(D_DIM * M_DIM) / 1024, 256, 0, stream>>>(
            w2 + (size_t)l * D_DIM * M_DIM, w2b, D_DIM * M_DIM);
        gemm_bt<2><<<dim3(D_DIM / 128, N_TOK / 128), 256, 0, stream>>>(
            a1b, w2b, bm2 + l * D_DIM, xf, hf, xf, nullptr, M_DIM, D_DIM);
    }
    ln_kernel<<<N_TOK, 256, 0, stream>>>(xf, gf, bfp, lnb);
    convert_kernel<<<(V_DIM * D_DIM) / 1024, 256, 0, stream>>>(wun, wunb, V_DIM * D_DIM);
    unembed_kernel<<<N_TOK / 128, 256, 0, stream>>>(lnb, wunb, bun, out);
}